// Round 6
// baseline (765.872 us; speedup 1.0000x reference)
//
#include <hip/hip_runtime.h>
#include <hip/hip_fp16.h>

constexpr int B = 4, C = 256, H = 64, W = 64, HW = 4096;
constexpr int K2 = 9, OFFC = 18;
constexpr int PSTR = 356;            // patch pair-stride in u32 (352 + 4 pad: != 0 mod 32)

typedef _Float16 f16x8 __attribute__((ext_vector_type(8)));
typedef float f32x4 __attribute__((ext_vector_type(4)));

__device__ __forceinline__ __half2 u2h(unsigned u) { return *reinterpret_cast<__half2*>(&u); }
__device__ __forceinline__ unsigned h2u(__half2 h) { return *reinterpret_cast<unsigned*>(&h); }
__device__ __forceinline__ unsigned packh2(float a, float b) {
  __half2 h = __floats2half2_rn(a, b);
  return *reinterpret_cast<unsigned*>(&h);
}

// ---------------- deform weights fp32 -> fp16, K reordered to cbi*288 + k*32 + c ----------------
__global__ void cvt_wf16_reord_k(const float* __restrict__ src, __half* __restrict__ dst) {
  int idx = blockIdx.x * 256 + threadIdx.x;
  if (idx >= 256 * 2304) return;
  int o = idx / 2304, kap = idx % 2304;
  int cbi = kap / 288, rem = kap % 288;
  int k = rem >> 5, c = rem & 31;
  dst[idx] = __float2half_rn(src[((size_t)(o * 256 + cbi * 32 + c)) * 9 + k]);
}

// ---------------- offset weights -> channel-pair fp16: owp[oc][cp][k] ----------------
__global__ void cvt_owpair_k(const float* __restrict__ src, unsigned* __restrict__ dst) {
  int idx = blockIdx.x * 256 + threadIdx.x;
  if (idx >= OFFC * 128 * 9) return;
  int k = idx % 9, cp = (idx / 9) & 127, oc = idx / 1152;
  dst[idx] = packh2(src[((size_t)oc * 256 + 2 * cp) * 9 + k],
                    src[((size_t)oc * 256 + 2 * cp + 1) * 9 + k]);
}

// ---------------- x fp32 NCHW -> channel-pair fp16 [b][c/2][px] ----------------
__global__ void cvt_xpair_k(const float* __restrict__ src, unsigned* __restrict__ dst) {
  int idx = blockIdx.x * 256 + threadIdx.x;      // B*128*1024
  int px4 = idx & 1023, c2 = (idx >> 10) & 127, b = idx >> 17;
  const float4 v0 = *reinterpret_cast<const float4*>(src + (((size_t)(b * 256 + 2 * c2)) << 12) + px4 * 4);
  const float4 v1 = *reinterpret_cast<const float4*>(src + (((size_t)(b * 256 + 2 * c2 + 1)) << 12) + px4 * 4);
  uint4 o = make_uint4(packh2(v0.x, v1.x), packh2(v0.y, v1.y), packh2(v0.z, v1.z), packh2(v0.w, v1.w));
  *reinterpret_cast<uint4*>(dst + (((size_t)(b * 128 + c2)) << 12) + px4 * 4) = o;
}

// ---------------- offset conv partials: fp16-pair input, __hfma2 inner ----------------
__launch_bounds__(256)
__global__ void offset_conv_k(const unsigned* __restrict__ xp, const unsigned* __restrict__ owp,
                              const float* __restrict__ ob, float* __restrict__ off4) {
  int cq = blockIdx.x & 3;
  int i  = (blockIdx.x >> 2) & 63;
  int b  = blockIdx.x >> 8;
  int t = threadIdx.x;
  int j = t & 63;
  int ocg = __builtin_amdgcn_readfirstlane(t >> 6);   // wave-uniform 0..3
  __shared__ unsigned xs[32][3][66];                   // 32 pairs x 3 rows x (64+halo)
  const unsigned* xb = xp + (size_t)b * 128 * HW;

  for (int pos = t; pos < 32 * 3 * 66; pos += 256) {
    int c = pos % 66, rp = pos / 66;
    int rr = rp % 3, p = rp / 3;
    int yy = i + rr - 1, xx = c - 1;
    unsigned v = 0;
    if (yy >= 0 && yy < H && xx >= 0 && xx < W)
      v = xb[(size_t)(cq * 32 + p) * HW + yy * 64 + xx];
    xs[p][rr][c] = v;
  }
  __syncthreads();

  float acc[5];
#pragma unroll
  for (int s = 0; s < 5; ++s) {
    int oc = ocg + 4 * s;
    acc[s] = (cq == 0 && oc < OFFC) ? ob[oc] : 0.f;
  }

  for (int p = 0; p < 32; ++p) {
    __half2 xv[9];
#pragma unroll
    for (int rr = 0; rr < 3; ++rr)
#pragma unroll
      for (int dxx = 0; dxx < 3; ++dxx) xv[rr * 3 + dxx] = u2h(xs[p][rr][j + dxx]);
#pragma unroll
    for (int s = 0; s < 5; ++s) {
      int oc = ocg + 4 * s;
      if (oc < OFFC) {
        const unsigned* wp = owp + ((size_t)oc * 128 + cq * 32 + p) * 9;   // uniform -> s_load
        __half2 h = __floats2half2_rn(0.f, 0.f);
#pragma unroll
        for (int k = 0; k < 9; ++k) h = __hfma2(xv[k], u2h(wp[k]), h);
        float2 f = __half22float2(h);
        acc[s] += f.x + f.y;
      }
    }
  }
#pragma unroll
  for (int s = 0; s < 5; ++s) {
    int oc = ocg + 4 * s;
    if (oc < OFFC)
      off4[(((size_t)(cq * B + b) * OFFC + oc) << 12) + (i << 6) + j] = acc[s];
  }
}

// ---------------- fused deformable conv (fp16 MFMA, LDS patch gather) ----------------
__launch_bounds__(512, 4)
__global__ void deform_mfma_k(const unsigned* __restrict__ xp, const float* __restrict__ off4,
                              const __half* __restrict__ wf,
                              const float* __restrict__ bias,
                              float* __restrict__ y, float* __restrict__ stats) {
  int jh = blockIdx.x & 1;
  int i  = (blockIdx.x >> 1) & 63;
  int b  = blockIdx.x >> 7;
  int t = threadIdx.x;
  int lane = t & 63, wv = t >> 6;        // 8 waves
  int cidx = lane & 15, r = lane >> 4;   // MFMA lane decomposition
  int jl = t & 31, cg = t >> 5;          // gather mapping: pixel jl, channel-pair cg (0..15)

  __shared__ __align__(16) unsigned s_md[K2][32][4];   // pre-broadcast half2 bilinear weights
  __shared__ __align__(8)  unsigned s_mf[K2][32][2];   // pb+flags, fallback
  __shared__ unsigned s_pt[2][16 * PSTR];              // patch dbuf: 16 pairs x (8x44 +pad)
  __shared__ __align__(16) unsigned s_su[32][148];     // sampled tile (fp16 pairs)
  __shared__ float rs_[8], rq_[8];

  const unsigned* xb = xp + (size_t)b * 128 * HW;
  int br = i - 3, bc = (jh << 5) - 5;     // patch origin

  int gof[11], wof[11];
#pragma unroll
  for (int e = 0; e < 11; ++e) {
    int pos = jl + (e << 5);
    int row = pos / 44, col = pos - row * 44;
    int rr = min(max(br + row, 0), H - 1);
    int c2 = min(max(bc + col, 0), W - 1);
    gof[e] = rr * 64 + c2;
    wof[e] = row * 44 + col;
  }

  // prologue: issue patch-0 loads (u32 fp16 pairs, no conversion)
  unsigned l[11];
  {
    const unsigned* bp = xb + (size_t)cg * HW;
#pragma unroll
    for (int e = 0; e < 11; ++e) l[e] = bp[gof[e]];
  }

  // Phase A: metadata (9 taps x 32 px)
  for (int idx = t; idx < K2 * 32; idx += 512) {
    int k = idx >> 5, jj = idx & 31;
    int j = (jh << 5) + jj;
    float dy = 0.f, dx = 0.f;
#pragma unroll
    for (int cq = 0; cq < 4; ++cq) {
      const float* p = off4 + (((size_t)(cq * B + b) * OFFC) << 12) + (i << 6) + j;
      dy += p[(2 * k) << 12];
      dx += p[(2 * k + 1) << 12];
    }
    float py = (float)(i + (k / 3) - 1) + dy;
    float px = (float)(j + (k % 3) - 1) + dx;
    float y0f = floorf(py), x0f = floorf(px);
    float wy1 = py - y0f, wx1 = px - x0f;
    float wy0 = 1.f - wy1, wx0 = 1.f - wx1;
    int y0 = (int)y0f, x0 = (int)x0f;
    if (y0 < 0 || y0 >= H)         wy0 = 0.f;
    if (y0 + 1 < 0 || y0 + 1 >= H) wy1 = 0.f;
    if (x0 < 0 || x0 >= W)         wx0 = 0.f;
    if (x0 + 1 < 0 || x0 + 1 >= W) wx1 = 0.f;
    int y0c = min(max(y0, 0), H - 1), y1c = min(max(y0 + 1, 0), H - 1);
    int x0c = min(max(x0, 0), W - 1), x1c = min(max(x0 + 1, 0), W - 1);
    int dys = y1c - y0c, dxs = x1c - x0c;
    uint4 wq;
    wq.x = h2u(__float2half2_rn(wy0 * wx0));
    wq.y = h2u(__float2half2_rn(wy0 * wx1));
    wq.z = h2u(__float2half2_rn(wy1 * wx0));
    wq.w = h2u(__float2half2_rn(wy1 * wx1));
    *reinterpret_cast<uint4*>(&s_md[k][jj][0]) = wq;
    bool ip = (y0c >= br) && (y1c <= br + 7) && (x0c >= bc) && (x1c <= bc + 43);
    unsigned pb = (unsigned)((y0c - br) * 44 + (x0c - bc));
    s_mf[k][jj][0] = (ip ? (pb & 0xfff) : 0u) | ((unsigned)dxs << 12) | ((unsigned)dys << 13) |
                     (ip ? 0u : 0x4000u);
    s_mf[k][jj][1] = (unsigned)(y0c * 64 + x0c) | ((unsigned)dxs << 12) | ((unsigned)dys << 13);
  }

  // write patch 0
#pragma unroll
  for (int e = 0; e < 11; ++e) s_pt[0][cg * PSTR + wof[e]] = l[e];
  __syncthreads();

  // hoist pb/fallback words (chunk-invariant) to registers
  unsigned pbf[9], fbk[9];
#pragma unroll
  for (int k = 0; k < K2; ++k) {
    uint2 mm = *reinterpret_cast<const uint2*>(&s_mf[k][jl][0]);
    pbf[k] = mm.x; fbk[k] = mm.y;
  }

  f32x4 acc[2][2];
#pragma unroll
  for (int m = 0; m < 2; ++m) {
    acc[m][0] = {0.f, 0.f, 0.f, 0.f};
    acc[m][1] = {0.f, 0.f, 0.f, 0.f};
  }
  int ob_ = wv * 32;
  const __half* w0p = wf + (size_t)(ob_ + cidx) * 2304;
  const __half* w1p = w0p + 16 * 2304;

  for (int cb = 0; cb < 8; ++cb) {
    int cur = cb & 1;
    if (cb < 7) {                                   // issue next patch loads early
      const unsigned* bp = xb + (size_t)((cb + 1) * 16 + cg) * HW;
#pragma unroll
      for (int e = 0; e < 11; ++e) l[e] = bp[gof[e]];
    }
    // gather+interp from patch (packed fp16, both channels at once)
    {
      const unsigned* pt = &s_pt[cur][cg * PSTR];
#pragma unroll
      for (int k = 0; k < K2; ++k) {
        uint4 m = *reinterpret_cast<const uint4*>(&s_md[k][jl][0]);
        unsigned z = pbf[k];
        int pb = z & 0xfff;
        int dxx = (z >> 12) & 1, dyy = ((z >> 13) & 1) ? 44 : 0;
        __half2 q00 = u2h(pt[pb]),        q01 = u2h(pt[pb + dxx]);
        __half2 q10 = u2h(pt[pb + dyy]),  q11 = u2h(pt[pb + dyy + dxx]);
        __half2 v = __hmul2(u2h(m.x), q00);
        v = __hfma2(u2h(m.y), q01, v);
        v = __hfma2(u2h(m.z), q10, v);
        v = __hfma2(u2h(m.w), q11, v);
        if (z & 0x4000u) {                          // rare: clamped corners escape patch
          unsigned f = fbk[k];
          int i00 = f & 0xfff;
          int fdx = (f >> 12) & 1, fdy = ((f >> 13) & 1) ? 64 : 0;
          const unsigned* xc = xb + (size_t)(cb * 16 + cg) * HW;
          v = __hmul2(u2h(m.x), u2h(xc[i00]));
          v = __hfma2(u2h(m.y), u2h(xc[i00 + fdx]), v);
          v = __hfma2(u2h(m.z), u2h(xc[i00 + fdy]), v);
          v = __hfma2(u2h(m.w), u2h(xc[i00 + fdy + fdx]), v);
        }
        s_su[jl][k * 16 + cg] = h2u(v);
      }
    }
    if (cb < 7) {                                   // write next patch
#pragma unroll
      for (int e = 0; e < 11; ++e) s_pt[cur ^ 1][cg * PSTR + wof[e]] = l[e];
    }
    __syncthreads();
    // MFMA: 9 K-steps (tap k x 32 ch)
    int kb0 = cb * 288 + r * 8;
#pragma unroll 3
    for (int kk = 0; kk < 9; ++kk) {
      f16x8 a0 = *(const f16x8*)&s_su[cidx][kk * 16 + r * 4];
      f16x8 a1 = *(const f16x8*)&s_su[16 + cidx][kk * 16 + r * 4];
      f16x8 b0 = *(const f16x8*)&w0p[kb0 + kk * 32];
      f16x8 b1 = *(const f16x8*)&w1p[kb0 + kk * 32];
      acc[0][0] = __builtin_amdgcn_mfma_f32_16x16x32_f16(a0, b0, acc[0][0], 0, 0, 0);
      acc[1][0] = __builtin_amdgcn_mfma_f32_16x16x32_f16(a1, b0, acc[1][0], 0, 0, 0);
      acc[0][1] = __builtin_amdgcn_mfma_f32_16x16x32_f16(a0, b1, acc[0][1], 0, 0, 0);
      acc[1][1] = __builtin_amdgcn_mfma_f32_16x16x32_f16(a1, b1, acc[1][1], 0, 0, 0);
    }
    __syncthreads();
  }

  // epilogue: bias, store, GN partial stats
  float bv0 = bias[ob_ + cidx], bv1 = bias[ob_ + 16 + cidx];
  float psum = 0.f, psq = 0.f;
#pragma unroll
  for (int m = 0; m < 2; ++m) {
#pragma unroll
    for (int n = 0; n < 2; ++n) {
      int o = ob_ + n * 16 + cidx;
      float bv = n ? bv1 : bv0;
      float4 vv;
      vv.x = acc[m][n][0] + bv; vv.y = acc[m][n][1] + bv;
      vv.z = acc[m][n][2] + bv; vv.w = acc[m][n][3] + bv;
      *reinterpret_cast<float4*>(y + (((size_t)(b * C + o)) << 12) + (i << 6) + (jh << 5) + m * 16 + r * 4) = vv;
      psum += vv.x + vv.y + vv.z + vv.w;
      psq  += vv.x * vv.x + vv.y * vv.y + vv.z * vv.z + vv.w * vv.w;
    }
  }
#pragma unroll
  for (int d = 32; d > 0; d >>= 1) {
    psum += __shfl_down(psum, d);
    psq  += __shfl_down(psq, d);
  }
  if (lane == 0) { rs_[wv] = psum; rq_[wv] = psq; }
  __syncthreads();
  if (t == 0) {
    float a = 0.f, s2 = 0.f;
    for (int u = 0; u < 8; ++u) { a += rs_[u]; s2 += rq_[u]; }
    atomicAdd(&stats[b * 2],     a);
    atomicAdd(&stats[b * 2 + 1], s2);
  }
}

// ---------------- GN + relu -> fp16-pair output (layer1 -> layer2 input) ----------------
__global__ void gn_pair_k(const float* __restrict__ yv, const float* __restrict__ stats,
                          const float* __restrict__ g, const float* __restrict__ be,
                          unsigned* __restrict__ outp) {
  const float inv = 1.f / (float)(C * HW);
  int idx = blockIdx.x * 256 + threadIdx.x;      // B*128*1024
  int px4 = idx & 1023, c2 = (idx >> 10) & 127, b = idx >> 17;
  float mean = stats[b * 2] * inv;
  float var  = stats[b * 2 + 1] * inv - mean * mean;
  float rs   = rsqrtf(var + 1e-5f);
  float a0 = g[2 * c2] * rs,     bb0 = be[2 * c2] - mean * a0;
  float a1 = g[2 * c2 + 1] * rs, bb1 = be[2 * c2 + 1] - mean * a1;
  const float4 v0 = *reinterpret_cast<const float4*>(yv + (((size_t)(b * 256 + 2 * c2)) << 12) + px4 * 4);
  const float4 v1 = *reinterpret_cast<const float4*>(yv + (((size_t)(b * 256 + 2 * c2 + 1)) << 12) + px4 * 4);
  uint4 o;
  o.x = packh2(fmaxf(0.f, v0.x * a0 + bb0), fmaxf(0.f, v1.x * a1 + bb1));
  o.y = packh2(fmaxf(0.f, v0.y * a0 + bb0), fmaxf(0.f, v1.y * a1 + bb1));
  o.z = packh2(fmaxf(0.f, v0.z * a0 + bb0), fmaxf(0.f, v1.z * a1 + bb1));
  o.w = packh2(fmaxf(0.f, v0.w * a0 + bb0), fmaxf(0.f, v1.w * a1 + bb1));
  *reinterpret_cast<uint4*>(outp + (((size_t)(b * 128 + c2)) << 12) + px4 * 4) = o;
}

// ---------------- fused: h2 = relu(gn2(yv)); z = h2 + x (in-place ok); stats(z) ----------------
__global__ void gn2res_k(const float* __restrict__ yv, const float* __restrict__ stats,
                         const float* __restrict__ g, const float* __restrict__ be,
                         const float* __restrict__ x, float* __restrict__ z,
                         float* __restrict__ stats3) {
  const float inv = 1.f / (float)(C * HW);
  int b = blockIdx.x >> 8;
  int seg = blockIdx.x & 255;
  size_t base = ((size_t)b << 20) + ((size_t)seg << 12);
  int t = threadIdx.x;
  float mean = stats[b * 2] * inv;
  float var  = stats[b * 2 + 1] * inv - mean * mean;
  float rsv  = rsqrtf(var + 1e-5f);
  int c = seg;                                    // seg 0..255 == channel
  float a = g[c] * rsv, bb = be[c] - mean * a;
  float psum = 0.f, psq = 0.f;
#pragma unroll
  for (int u = 0; u < 4; ++u) {
    size_t e = base + (size_t)(u * 256 + t) * 4;
    float4 v = *reinterpret_cast<const float4*>(yv + e);
    float4 xr = *reinterpret_cast<const float4*>(x + e);
    float4 rr;
    rr.x = fmaxf(0.f, v.x * a + bb) + xr.x;
    rr.y = fmaxf(0.f, v.y * a + bb) + xr.y;
    rr.z = fmaxf(0.f, v.z * a + bb) + xr.z;
    rr.w = fmaxf(0.f, v.w * a + bb) + xr.w;
    *reinterpret_cast<float4*>(z + e) = rr;
    psum += rr.x + rr.y + rr.z + rr.w;
    psq  += rr.x * rr.x + rr.y * rr.y + rr.z * rr.z + rr.w * rr.w;
  }
#pragma unroll
  for (int d = 32; d > 0; d >>= 1) {
    psum += __shfl_down(psum, d);
    psq  += __shfl_down(psq, d);
  }
  __shared__ float rs_[4], rq_[4];
  int wid = t >> 6, lane = t & 63;
  if (lane == 0) { rs_[wid] = psum; rq_[wid] = psq; }
  __syncthreads();
  if (t == 0) {
    float aa = 0.f, s2 = 0.f;
    for (int u = 0; u < 4; ++u) { aa += rs_[u]; s2 += rq_[u]; }
    atomicAdd(&stats3[b * 2],     aa);
    atomicAdd(&stats3[b * 2 + 1], s2);
  }
}

// ---------------- final group-norm (fp32 out) ----------------
__global__ void gn_k(const float* __restrict__ yv, const float* __restrict__ stats,
                     const float* __restrict__ g, const float* __restrict__ be,
                     float* __restrict__ outp) {
  const float inv = 1.f / (float)(C * HW);
  int stride = gridDim.x * blockDim.x;
  int total4 = B * C * HW / 4;
  for (int idx = blockIdx.x * blockDim.x + threadIdx.x; idx < total4; idx += stride) {
    int e = idx << 2;
    int b = e >> 20;
    int c = (e >> 12) & 255;
    float mean = stats[b * 2] * inv;
    float var  = stats[b * 2 + 1] * inv - mean * mean;
    float rs   = rsqrtf(var + 1e-5f);
    float a  = g[c] * rs;
    float b2 = be[c] - mean * a;
    float4 v = *reinterpret_cast<const float4*>(yv + e);
    float4 rr;
    rr.x = v.x * a + b2; rr.y = v.y * a + b2; rr.z = v.z * a + b2; rr.w = v.w * a + b2;
    *reinterpret_cast<float4*>(outp + e) = rr;
  }
}

extern "C" void kernel_launch(void* const* d_in, const int* in_sizes, int n_in,
                              void* d_out, int out_size, void* d_ws, size_t ws_size,
                              hipStream_t stream) {
  const float* x   = (const float*)d_in[0];
  const float* ow1 = (const float*)d_in[1];
  const float* ob1 = (const float*)d_in[2];
  const float* dw1 = (const float*)d_in[3];
  const float* db1 = (const float*)d_in[4];
  const float* g1  = (const float*)d_in[5];
  const float* b1  = (const float*)d_in[6];
  const float* ow2 = (const float*)d_in[7];
  const float* ob2 = (const float*)d_in[8];
  const float* dw2 = (const float*)d_in[9];
  const float* db2 = (const float*)d_in[10];
  const float* g2  = (const float*)d_in[11];
  const float* b2  = (const float*)d_in[12];
  const float* g3  = (const float*)d_in[13];
  const float* b3  = (const float*)d_in[14];

  float* ws   = (float*)d_ws;
  float* off4 = ws;                                   // 1179648 f
  float* yb   = ws + 1179648;                         // 4194304 f
  float* st   = ws + 1179648 + 4194304;               // 32 f
  unsigned* xh = (unsigned*)(ws + 5373984);           // 2097152 u32
  unsigned* hh = (unsigned*)(ws + 7471136);           // 2097152 u32
  __half* wf1 = (__half*)(ws + 9568288);              // 589824 fp16 = 294912 f
  __half* wf2 = (__half*)(ws + 9863200);
  unsigned* owp1 = (unsigned*)(ws + 10158112);        // 20736 u32
  unsigned* owp2 = (unsigned*)(ws + 10178848);
  float* outp = (float*)d_out;

  hipMemsetAsync(st, 0, 32 * sizeof(float), stream);
  cvt_wf16_reord_k<<<2304, 256, 0, stream>>>(dw1, wf1);
  cvt_wf16_reord_k<<<2304, 256, 0, stream>>>(dw2, wf2);
  cvt_owpair_k<<<81, 256, 0, stream>>>(ow1, owp1);
  cvt_owpair_k<<<81, 256, 0, stream>>>(ow2, owp2);
  cvt_xpair_k<<<2048, 256, 0, stream>>>(x, xh);

  // layer 1
  offset_conv_k<<<1024, 256, 0, stream>>>(xh, owp1, ob1, off4);
  deform_mfma_k<<<512, 512, 0, stream>>>(xh, off4, wf1, db1, yb, st + 0);
  gn_pair_k<<<2048, 256, 0, stream>>>(yb, st + 0, g1, b1, hh);
  // layer 2
  offset_conv_k<<<1024, 256, 0, stream>>>(hh, owp2, ob2, off4);
  deform_mfma_k<<<512, 512, 0, stream>>>(hh, off4, wf2, db2, yb, st + 8);
  // fused gn2 + relu + residual (in-place on yb) + final stats
  gn2res_k<<<1024, 256, 0, stream>>>(yb, st + 8, g2, b2, x, yb, st + 16);
  gn_k<<<2048, 256, 0, stream>>>(yb, st + 16, g3, b3, outp);
}

// Round 8
// 458.580 us; speedup vs baseline: 1.6701x; 1.6701x over previous
//
#include <hip/hip_runtime.h>
#include <hip/hip_fp16.h>

constexpr int B = 4, C = 256, H = 64, W = 64, HW = 4096;
constexpr int K2 = 9, OFFC = 18;
constexpr int PSTR = 356;            // patch pair-stride in u32 (352 + 4 pad: != 0 mod 32)

typedef _Float16 f16x8 __attribute__((ext_vector_type(8)));
typedef float f32x4 __attribute__((ext_vector_type(4)));

__device__ __forceinline__ __half2 u2h(unsigned u) { return *reinterpret_cast<__half2*>(&u); }
__device__ __forceinline__ unsigned h2u(__half2 h) { return *reinterpret_cast<unsigned*>(&h); }
__device__ __forceinline__ unsigned packh2(float a, float b) {
  __half2 h = __floats2half2_rn(a, b);
  return *reinterpret_cast<unsigned*>(&h);
}

// ---------------- deform weights fp32 -> fp16, K reordered to cbi*288 + k*32 + c ----------------
__global__ void cvt_wf16_reord_k(const float* __restrict__ src, __half* __restrict__ dst) {
  int idx = blockIdx.x * 256 + threadIdx.x;
  if (idx >= 256 * 2304) return;
  int o = idx / 2304, kap = idx % 2304;
  int cbi = kap / 288, rem = kap % 288;
  int k = rem >> 5, c = rem & 31;
  dst[idx] = __float2half_rn(src[((size_t)(o * 256 + cbi * 32 + c)) * 9 + k]);
}

// ---------------- offset weights -> channel-pair fp16: owp[oc][cp][k] ----------------
__global__ void cvt_owpair_k(const float* __restrict__ src, unsigned* __restrict__ dst) {
  int idx = blockIdx.x * 256 + threadIdx.x;
  if (idx >= OFFC * 128 * 9) return;
  int k = idx % 9, cp = (idx / 9) & 127, oc = idx / 1152;
  dst[idx] = packh2(src[((size_t)oc * 256 + 2 * cp) * 9 + k],
                    src[((size_t)oc * 256 + 2 * cp + 1) * 9 + k]);
}

// ---------------- x fp32 NCHW -> channel-pair fp16 [b][c/2][px] ----------------
__global__ void cvt_xpair_k(const float* __restrict__ src, unsigned* __restrict__ dst) {
  int idx = blockIdx.x * 256 + threadIdx.x;      // B*128*1024
  int px4 = idx & 1023, c2 = (idx >> 10) & 127, b = idx >> 17;
  const float4 v0 = *reinterpret_cast<const float4*>(src + (((size_t)(b * 256 + 2 * c2)) << 12) + px4 * 4);
  const float4 v1 = *reinterpret_cast<const float4*>(src + (((size_t)(b * 256 + 2 * c2 + 1)) << 12) + px4 * 4);
  uint4 o = make_uint4(packh2(v0.x, v1.x), packh2(v0.y, v1.y), packh2(v0.z, v1.z), packh2(v0.w, v1.w));
  *reinterpret_cast<uint4*>(dst + (((size_t)(b * 128 + c2)) << 12) + px4 * 4) = o;
}

// ---------------- offset conv partials: fp16-pair input, __hfma2 inner ----------------
__launch_bounds__(256)
__global__ void offset_conv_k(const unsigned* __restrict__ xp, const unsigned* __restrict__ owp,
                              const float* __restrict__ ob, float* __restrict__ off4) {
  int cq = blockIdx.x & 3;
  int i  = (blockIdx.x >> 2) & 63;
  int b  = blockIdx.x >> 8;
  int t = threadIdx.x;
  int j = t & 63;
  int ocg = __builtin_amdgcn_readfirstlane(t >> 6);   // wave-uniform 0..3
  __shared__ unsigned xs[32][3][66];                   // 32 pairs x 3 rows x (64+halo)
  const unsigned* xb = xp + (size_t)b * 128 * HW;

  for (int pos = t; pos < 32 * 3 * 66; pos += 256) {
    int c = pos % 66, rp = pos / 66;
    int rr = rp % 3, p = rp / 3;
    int yy = i + rr - 1, xx = c - 1;
    unsigned v = 0;
    if (yy >= 0 && yy < H && xx >= 0 && xx < W)
      v = xb[(size_t)(cq * 32 + p) * HW + yy * 64 + xx];
    xs[p][rr][c] = v;
  }
  __syncthreads();

  float acc[5];
#pragma unroll
  for (int s = 0; s < 5; ++s) {
    int oc = ocg + 4 * s;
    acc[s] = (cq == 0 && oc < OFFC) ? ob[oc] : 0.f;
  }

  for (int p = 0; p < 32; ++p) {
    __half2 xv[9];
#pragma unroll
    for (int rr = 0; rr < 3; ++rr)
#pragma unroll
      for (int dxx = 0; dxx < 3; ++dxx) xv[rr * 3 + dxx] = u2h(xs[p][rr][j + dxx]);
#pragma unroll
    for (int s = 0; s < 5; ++s) {
      int oc = ocg + 4 * s;
      if (oc < OFFC) {
        const unsigned* wp = owp + ((size_t)oc * 128 + cq * 32 + p) * 9;   // uniform -> s_load
        __half2 h = __floats2half2_rn(0.f, 0.f);
#pragma unroll
        for (int k = 0; k < 9; ++k) h = __hfma2(xv[k], u2h(wp[k]), h);
        float2 f = __half22float2(h);
        acc[s] += f.x + f.y;
      }
    }
  }
#pragma unroll
  for (int s = 0; s < 5; ++s) {
    int oc = ocg + 4 * s;
    if (oc < OFFC)
      off4[(((size_t)(cq * B + b) * OFFC + oc) << 12) + (i << 6) + j] = acc[s];
  }
}

// ---------------- fused deformable conv (fp16 MFMA, LDS patch gather) ----------------
// NOTE: no min-occupancy hint! (512,4) made hipcc cap VGPR at 64 -> catastrophic
// scratch spills (676 MB WRITE_SIZE). LDS (71.7KB) already caps at 2 blocks/CU,
// which needs only VGPR<=128 -- let the allocator breathe.
__launch_bounds__(512)
__global__ void deform_mfma_k(const unsigned* __restrict__ xp, const float* __restrict__ off4,
                              const __half* __restrict__ wf,
                              const float* __restrict__ bias,
                              float* __restrict__ y, float* __restrict__ stats) {
  int jh = blockIdx.x & 1;
  int i  = (blockIdx.x >> 1) & 63;
  int b  = blockIdx.x >> 7;
  int t = threadIdx.x;
  int lane = t & 63, wv = t >> 6;        // 8 waves
  int cidx = lane & 15, r = lane >> 4;   // MFMA lane decomposition
  int jl = t & 31, cg = t >> 5;          // gather mapping: pixel jl, channel-pair cg (0..15)

  __shared__ __align__(16) unsigned s_md[K2][32][4];   // pre-broadcast half2 bilinear weights
  __shared__ __align__(8)  unsigned s_mf[K2][32][2];   // pb+flags, fallback
  __shared__ unsigned s_pt[2][16 * PSTR];              // patch dbuf: 16 pairs x (8x44 +pad)
  __shared__ __align__(16) unsigned s_su[32][148];     // sampled tile (fp16 pairs)
  __shared__ float rs_[8], rq_[8];

  const unsigned* xb = xp + (size_t)b * 128 * HW;
  int br = i - 3, bc = (jh << 5) - 5;     // patch origin

  int gof[11], wof[11];
#pragma unroll
  for (int e = 0; e < 11; ++e) {
    int pos = jl + (e << 5);
    int row = pos / 44, col = pos - row * 44;
    int rr = min(max(br + row, 0), H - 1);
    int c2 = min(max(bc + col, 0), W - 1);
    gof[e] = rr * 64 + c2;
    wof[e] = row * 44 + col;
  }

  // prologue: issue patch-0 loads (u32 fp16 pairs, no conversion)
  unsigned l[11];
  {
    const unsigned* bp = xb + (size_t)cg * HW;
#pragma unroll
    for (int e = 0; e < 11; ++e) l[e] = bp[gof[e]];
  }

  // Phase A: metadata (9 taps x 32 px)
  for (int idx = t; idx < K2 * 32; idx += 512) {
    int k = idx >> 5, jj = idx & 31;
    int j = (jh << 5) + jj;
    float dy = 0.f, dx = 0.f;
#pragma unroll
    for (int cq = 0; cq < 4; ++cq) {
      const float* p = off4 + (((size_t)(cq * B + b) * OFFC) << 12) + (i << 6) + j;
      dy += p[(2 * k) << 12];
      dx += p[(2 * k + 1) << 12];
    }
    float py = (float)(i + (k / 3) - 1) + dy;
    float px = (float)(j + (k % 3) - 1) + dx;
    float y0f = floorf(py), x0f = floorf(px);
    float wy1 = py - y0f, wx1 = px - x0f;
    float wy0 = 1.f - wy1, wx0 = 1.f - wx1;
    int y0 = (int)y0f, x0 = (int)x0f;
    if (y0 < 0 || y0 >= H)         wy0 = 0.f;
    if (y0 + 1 < 0 || y0 + 1 >= H) wy1 = 0.f;
    if (x0 < 0 || x0 >= W)         wx0 = 0.f;
    if (x0 + 1 < 0 || x0 + 1 >= W) wx1 = 0.f;
    int y0c = min(max(y0, 0), H - 1), y1c = min(max(y0 + 1, 0), H - 1);
    int x0c = min(max(x0, 0), W - 1), x1c = min(max(x0 + 1, 0), W - 1);
    int dys = y1c - y0c, dxs = x1c - x0c;
    uint4 wq;
    wq.x = h2u(__float2half2_rn(wy0 * wx0));
    wq.y = h2u(__float2half2_rn(wy0 * wx1));
    wq.z = h2u(__float2half2_rn(wy1 * wx0));
    wq.w = h2u(__float2half2_rn(wy1 * wx1));
    *reinterpret_cast<uint4*>(&s_md[k][jj][0]) = wq;
    bool ip = (y0c >= br) && (y1c <= br + 7) && (x0c >= bc) && (x1c <= bc + 43);
    unsigned pb = (unsigned)((y0c - br) * 44 + (x0c - bc));
    s_mf[k][jj][0] = (ip ? (pb & 0xfff) : 0u) | ((unsigned)dxs << 12) | ((unsigned)dys << 13) |
                     (ip ? 0u : 0x4000u);
    s_mf[k][jj][1] = (unsigned)(y0c * 64 + x0c) | ((unsigned)dxs << 12) | ((unsigned)dys << 13);
  }

  // write patch 0
#pragma unroll
  for (int e = 0; e < 11; ++e) s_pt[0][cg * PSTR + wof[e]] = l[e];
  __syncthreads();

  // hoist pb/fallback words (chunk-invariant) to registers
  unsigned pbf[9], fbk[9];
#pragma unroll
  for (int k = 0; k < K2; ++k) {
    uint2 mm = *reinterpret_cast<const uint2*>(&s_mf[k][jl][0]);
    pbf[k] = mm.x; fbk[k] = mm.y;
  }

  f32x4 acc[2][2];
#pragma unroll
  for (int m = 0; m < 2; ++m) {
    acc[m][0] = {0.f, 0.f, 0.f, 0.f};
    acc[m][1] = {0.f, 0.f, 0.f, 0.f};
  }
  int ob_ = wv * 32;
  const __half* w0p = wf + (size_t)(ob_ + cidx) * 2304;
  const __half* w1p = w0p + 16 * 2304;

  for (int cb = 0; cb < 8; ++cb) {
    int cur = cb & 1;
    if (cb < 7) {                                   // issue next patch loads early
      const unsigned* bp = xb + (size_t)((cb + 1) * 16 + cg) * HW;
#pragma unroll
      for (int e = 0; e < 11; ++e) l[e] = bp[gof[e]];
    }
    // gather+interp from patch (packed fp16, both channels at once)
    {
      const unsigned* pt = &s_pt[cur][cg * PSTR];
#pragma unroll
      for (int k = 0; k < K2; ++k) {
        uint4 m = *reinterpret_cast<const uint4*>(&s_md[k][jl][0]);
        unsigned z = pbf[k];
        int pb = z & 0xfff;
        int dxx = (z >> 12) & 1, dyy = ((z >> 13) & 1) ? 44 : 0;
        __half2 q00 = u2h(pt[pb]),        q01 = u2h(pt[pb + dxx]);
        __half2 q10 = u2h(pt[pb + dyy]),  q11 = u2h(pt[pb + dyy + dxx]);
        __half2 v = __hmul2(u2h(m.x), q00);
        v = __hfma2(u2h(m.y), q01, v);
        v = __hfma2(u2h(m.z), q10, v);
        v = __hfma2(u2h(m.w), q11, v);
        if (z & 0x4000u) {                          // rare: clamped corners escape patch
          unsigned f = fbk[k];
          int i00 = f & 0xfff;
          int fdx = (f >> 12) & 1, fdy = ((f >> 13) & 1) ? 64 : 0;
          const unsigned* xc = xb + (size_t)(cb * 16 + cg) * HW;
          v = __hmul2(u2h(m.x), u2h(xc[i00]));
          v = __hfma2(u2h(m.y), u2h(xc[i00 + fdx]), v);
          v = __hfma2(u2h(m.z), u2h(xc[i00 + fdy]), v);
          v = __hfma2(u2h(m.w), u2h(xc[i00 + fdy + fdx]), v);
        }
        s_su[jl][k * 16 + cg] = h2u(v);
      }
    }
    if (cb < 7) {                                   // write next patch
#pragma unroll
      for (int e = 0; e < 11; ++e) s_pt[cur ^ 1][cg * PSTR + wof[e]] = l[e];
    }
    __syncthreads();
    // MFMA: 9 K-steps (tap k x 32 ch)
    int kb0 = cb * 288 + r * 8;
#pragma unroll 3
    for (int kk = 0; kk < 9; ++kk) {
      f16x8 a0 = *(const f16x8*)&s_su[cidx][kk * 16 + r * 4];
      f16x8 a1 = *(const f16x8*)&s_su[16 + cidx][kk * 16 + r * 4];
      f16x8 b0 = *(const f16x8*)&w0p[kb0 + kk * 32];
      f16x8 b1 = *(const f16x8*)&w1p[kb0 + kk * 32];
      acc[0][0] = __builtin_amdgcn_mfma_f32_16x16x32_f16(a0, b0, acc[0][0], 0, 0, 0);
      acc[1][0] = __builtin_amdgcn_mfma_f32_16x16x32_f16(a1, b0, acc[1][0], 0, 0, 0);
      acc[0][1] = __builtin_amdgcn_mfma_f32_16x16x32_f16(a0, b1, acc[0][1], 0, 0, 0);
      acc[1][1] = __builtin_amdgcn_mfma_f32_16x16x32_f16(a1, b1, acc[1][1], 0, 0, 0);
    }
    __syncthreads();
  }

  // epilogue: bias, store, GN partial stats
  float bv0 = bias[ob_ + cidx], bv1 = bias[ob_ + 16 + cidx];
  float psum = 0.f, psq = 0.f;
#pragma unroll
  for (int m = 0; m < 2; ++m) {
#pragma unroll
    for (int n = 0; n < 2; ++n) {
      int o = ob_ + n * 16 + cidx;
      float bv = n ? bv1 : bv0;
      float4 vv;
      vv.x = acc[m][n][0] + bv; vv.y = acc[m][n][1] + bv;
      vv.z = acc[m][n][2] + bv; vv.w = acc[m][n][3] + bv;
      *reinterpret_cast<float4*>(y + (((size_t)(b * C + o)) << 12) + (i << 6) + (jh << 5) + m * 16 + r * 4) = vv;
      psum += vv.x + vv.y + vv.z + vv.w;
      psq  += vv.x * vv.x + vv.y * vv.y + vv.z * vv.z + vv.w * vv.w;
    }
  }
#pragma unroll
  for (int d = 32; d > 0; d >>= 1) {
    psum += __shfl_down(psum, d);
    psq  += __shfl_down(psq, d);
  }
  if (lane == 0) { rs_[wv] = psum; rq_[wv] = psq; }
  __syncthreads();
  if (t == 0) {
    float a = 0.f, s2 = 0.f;
    for (int u = 0; u < 8; ++u) { a += rs_[u]; s2 += rq_[u]; }
    atomicAdd(&stats[b * 2],     a);
    atomicAdd(&stats[b * 2 + 1], s2);
  }
}

// ---------------- GN + relu -> fp16-pair output (layer1 -> layer2 input) ----------------
__global__ void gn_pair_k(const float* __restrict__ yv, const float* __restrict__ stats,
                          const float* __restrict__ g, const float* __restrict__ be,
                          unsigned* __restrict__ outp) {
  const float inv = 1.f / (float)(C * HW);
  int idx = blockIdx.x * 256 + threadIdx.x;      // B*128*1024
  int px4 = idx & 1023, c2 = (idx >> 10) & 127, b = idx >> 17;
  float mean = stats[b * 2] * inv;
  float var  = stats[b * 2 + 1] * inv - mean * mean;
  float rs   = rsqrtf(var + 1e-5f);
  float a0 = g[2 * c2] * rs,     bb0 = be[2 * c2] - mean * a0;
  float a1 = g[2 * c2 + 1] * rs, bb1 = be[2 * c2 + 1] - mean * a1;
  const float4 v0 = *reinterpret_cast<const float4*>(yv + (((size_t)(b * 256 + 2 * c2)) << 12) + px4 * 4);
  const float4 v1 = *reinterpret_cast<const float4*>(yv + (((size_t)(b * 256 + 2 * c2 + 1)) << 12) + px4 * 4);
  uint4 o;
  o.x = packh2(fmaxf(0.f, v0.x * a0 + bb0), fmaxf(0.f, v1.x * a1 + bb1));
  o.y = packh2(fmaxf(0.f, v0.y * a0 + bb0), fmaxf(0.f, v1.y * a1 + bb1));
  o.z = packh2(fmaxf(0.f, v0.z * a0 + bb0), fmaxf(0.f, v1.z * a1 + bb1));
  o.w = packh2(fmaxf(0.f, v0.w * a0 + bb0), fmaxf(0.f, v1.w * a1 + bb1));
  *reinterpret_cast<uint4*>(outp + (((size_t)(b * 128 + c2)) << 12) + px4 * 4) = o;
}

// ---------------- fused: h2 = relu(gn2(yv)); z = h2 + x (in-place ok); stats(z) ----------------
__global__ void gn2res_k(const float* __restrict__ yv, const float* __restrict__ stats,
                         const float* __restrict__ g, const float* __restrict__ be,
                         const float* __restrict__ x, float* __restrict__ z,
                         float* __restrict__ stats3) {
  const float inv = 1.f / (float)(C * HW);
  int b = blockIdx.x >> 8;
  int seg = blockIdx.x & 255;
  size_t base = ((size_t)b << 20) + ((size_t)seg << 12);
  int t = threadIdx.x;
  float mean = stats[b * 2] * inv;
  float var  = stats[b * 2 + 1] * inv - mean * mean;
  float rsv  = rsqrtf(var + 1e-5f);
  int c = seg;                                    // seg 0..255 == channel
  float a = g[c] * rsv, bb = be[c] - mean * a;
  float psum = 0.f, psq = 0.f;
#pragma unroll
  for (int u = 0; u < 4; ++u) {
    size_t e = base + (size_t)(u * 256 + t) * 4;
    float4 v = *reinterpret_cast<const float4*>(yv + e);
    float4 xr = *reinterpret_cast<const float4*>(x + e);
    float4 rr;
    rr.x = fmaxf(0.f, v.x * a + bb) + xr.x;
    rr.y = fmaxf(0.f, v.y * a + bb) + xr.y;
    rr.z = fmaxf(0.f, v.z * a + bb) + xr.z;
    rr.w = fmaxf(0.f, v.w * a + bb) + xr.w;
    *reinterpret_cast<float4*>(z + e) = rr;
    psum += rr.x + rr.y + rr.z + rr.w;
    psq  += rr.x * rr.x + rr.y * rr.y + rr.z * rr.z + rr.w * rr.w;
  }
#pragma unroll
  for (int d = 32; d > 0; d >>= 1) {
    psum += __shfl_down(psum, d);
    psq  += __shfl_down(psq, d);
  }
  __shared__ float rs_[4], rq_[4];
  int wid = t >> 6, lane = t & 63;
  if (lane == 0) { rs_[wid] = psum; rq_[wid] = psq; }
  __syncthreads();
  if (t == 0) {
    float aa = 0.f, s2 = 0.f;
    for (int u = 0; u < 4; ++u) { aa += rs_[u]; s2 += rq_[u]; }
    atomicAdd(&stats3[b * 2],     aa);
    atomicAdd(&stats3[b * 2 + 1], s2);
  }
}

// ---------------- final group-norm (fp32 out) ----------------
__global__ void gn_k(const float* __restrict__ yv, const float* __restrict__ stats,
                     const float* __restrict__ g, const float* __restrict__ be,
                     float* __restrict__ outp) {
  const float inv = 1.f / (float)(C * HW);
  int stride = gridDim.x * blockDim.x;
  int total4 = B * C * HW / 4;
  for (int idx = blockIdx.x * blockDim.x + threadIdx.x; idx < total4; idx += stride) {
    int e = idx << 2;
    int b = e >> 20;
    int c = (e >> 12) & 255;
    float mean = stats[b * 2] * inv;
    float var  = stats[b * 2 + 1] * inv - mean * mean;
    float rs   = rsqrtf(var + 1e-5f);
    float a  = g[c] * rs;
    float b2 = be[c] - mean * a;
    float4 v = *reinterpret_cast<const float4*>(yv + e);
    float4 rr;
    rr.x = v.x * a + b2; rr.y = v.y * a + b2; rr.z = v.z * a + b2; rr.w = v.w * a + b2;
    *reinterpret_cast<float4*>(outp + e) = rr;
  }
}

extern "C" void kernel_launch(void* const* d_in, const int* in_sizes, int n_in,
                              void* d_out, int out_size, void* d_ws, size_t ws_size,
                              hipStream_t stream) {
  const float* x   = (const float*)d_in[0];
  const float* ow1 = (const float*)d_in[1];
  const float* ob1 = (const float*)d_in[2];
  const float* dw1 = (const float*)d_in[3];
  const float* db1 = (const float*)d_in[4];
  const float* g1  = (const float*)d_in[5];
  const float* b1  = (const float*)d_in[6];
  const float* ow2 = (const float*)d_in[7];
  const float* ob2 = (const float*)d_in[8];
  const float* dw2 = (const float*)d_in[9];
  const float* db2 = (const float*)d_in[10];
  const float* g2  = (const float*)d_in[11];
  const float* b2  = (const float*)d_in[12];
  const float* g3  = (const float*)d_in[13];
  const float* b3  = (const float*)d_in[14];

  float* ws   = (float*)d_ws;
  float* off4 = ws;                                   // 1179648 f
  float* yb   = ws + 1179648;                         // 4194304 f
  float* st   = ws + 1179648 + 4194304;               // 32 f
  unsigned* xh = (unsigned*)(ws + 5373984);           // 2097152 u32
  unsigned* hh = (unsigned*)(ws + 7471136);           // 2097152 u32
  __half* wf1 = (__half*)(ws + 9568288);              // 589824 fp16 = 294912 f
  __half* wf2 = (__half*)(ws + 9863200);
  unsigned* owp1 = (unsigned*)(ws + 10158112);        // 20736 u32
  unsigned* owp2 = (unsigned*)(ws + 10178848);
  float* outp = (float*)d_out;

  hipMemsetAsync(st, 0, 32 * sizeof(float), stream);
  cvt_wf16_reord_k<<<2304, 256, 0, stream>>>(dw1, wf1);
  cvt_wf16_reord_k<<<2304, 256, 0, stream>>>(dw2, wf2);
  cvt_owpair_k<<<81, 256, 0, stream>>>(ow1, owp1);
  cvt_owpair_k<<<81, 256, 0, stream>>>(ow2, owp2);
  cvt_xpair_k<<<2048, 256, 0, stream>>>(x, xh);

  // layer 1
  offset_conv_k<<<1024, 256, 0, stream>>>(xh, owp1, ob1, off4);
  deform_mfma_k<<<512, 512, 0, stream>>>(xh, off4, wf1, db1, yb, st + 0);
  gn_pair_k<<<2048, 256, 0, stream>>>(yb, st + 0, g1, b1, hh);
  // layer 2
  offset_conv_k<<<1024, 256, 0, stream>>>(hh, owp2, ob2, off4);
  deform_mfma_k<<<512, 512, 0, stream>>>(hh, off4, wf2, db2, yb, st + 8);
  // fused gn2 + relu + residual (in-place on yb) + final stats
  gn2res_k<<<1024, 256, 0, stream>>>(yb, st + 8, g2, b2, x, yb, st + 16);
  gn_k<<<2048, 256, 0, stream>>>(yb, st + 16, g3, b3, outp);
}

// Round 9
// 450.043 us; speedup vs baseline: 1.7018x; 1.0190x over previous
//
#include <hip/hip_runtime.h>
#include <hip/hip_fp16.h>

constexpr int B = 4, C = 256, H = 64, W = 64, HW = 4096;
constexpr int K2 = 9, OFFC = 18;
constexpr int PSTR = 268;            // patch pair-stride in u32 (6*44=264 + 4 pad; 268%32=12)

typedef _Float16 f16x8 __attribute__((ext_vector_type(8)));
typedef float f32x4 __attribute__((ext_vector_type(4)));

__device__ __forceinline__ __half2 u2h(unsigned u) { return *reinterpret_cast<__half2*>(&u); }
__device__ __forceinline__ unsigned h2u(__half2 h) { return *reinterpret_cast<unsigned*>(&h); }
__device__ __forceinline__ unsigned packh2(float a, float b) {
  __half2 h = __floats2half2_rn(a, b);
  return *reinterpret_cast<unsigned*>(&h);
}

// ---------------- deform weights fp32 -> fp16, K reordered to cbi*288 + k*32 + c ----------------
__global__ void cvt_wf16_reord_k(const float* __restrict__ src, __half* __restrict__ dst) {
  int idx = blockIdx.x * 256 + threadIdx.x;
  if (idx >= 256 * 2304) return;
  int o = idx / 2304, kap = idx % 2304;
  int cbi = kap / 288, rem = kap % 288;
  int k = rem >> 5, c = rem & 31;
  dst[idx] = __float2half_rn(src[((size_t)(o * 256 + cbi * 32 + c)) * 9 + k]);
}

// ---------------- offset weights -> channel-pair fp16: owp[oc][cp][k] ----------------
__global__ void cvt_owpair_k(const float* __restrict__ src, unsigned* __restrict__ dst) {
  int idx = blockIdx.x * 256 + threadIdx.x;
  if (idx >= OFFC * 128 * 9) return;
  int k = idx % 9, cp = (idx / 9) & 127, oc = idx / 1152;
  dst[idx] = packh2(src[((size_t)oc * 256 + 2 * cp) * 9 + k],
                    src[((size_t)oc * 256 + 2 * cp + 1) * 9 + k]);
}

// ---------------- x fp32 NCHW -> channel-pair fp16 [b][c/2][px] ----------------
__global__ void cvt_xpair_k(const float* __restrict__ src, unsigned* __restrict__ dst) {
  int idx = blockIdx.x * 256 + threadIdx.x;      // B*128*1024
  int px4 = idx & 1023, c2 = (idx >> 10) & 127, b = idx >> 17;
  const float4 v0 = *reinterpret_cast<const float4*>(src + (((size_t)(b * 256 + 2 * c2)) << 12) + px4 * 4);
  const float4 v1 = *reinterpret_cast<const float4*>(src + (((size_t)(b * 256 + 2 * c2 + 1)) << 12) + px4 * 4);
  uint4 o = make_uint4(packh2(v0.x, v1.x), packh2(v0.y, v1.y), packh2(v0.z, v1.z), packh2(v0.w, v1.w));
  *reinterpret_cast<uint4*>(dst + (((size_t)(b * 128 + c2)) << 12) + px4 * 4) = o;
}

// ---------------- offset conv partials: fp16-pair input, __hfma2 inner ----------------
__launch_bounds__(256)
__global__ void offset_conv_k(const unsigned* __restrict__ xp, const unsigned* __restrict__ owp,
                              const float* __restrict__ ob, float* __restrict__ off4) {
  int cq = blockIdx.x & 3;
  int i  = (blockIdx.x >> 2) & 63;
  int b  = blockIdx.x >> 8;
  int t = threadIdx.x;
  int j = t & 63;
  int ocg = __builtin_amdgcn_readfirstlane(t >> 6);   // wave-uniform 0..3
  __shared__ unsigned xs[32][3][66];                   // 32 pairs x 3 rows x (64+halo)
  const unsigned* xb = xp + (size_t)b * 128 * HW;

  for (int pos = t; pos < 32 * 3 * 66; pos += 256) {
    int c = pos % 66, rp = pos / 66;
    int rr = rp % 3, p = rp / 3;
    int yy = i + rr - 1, xx = c - 1;
    unsigned v = 0;
    if (yy >= 0 && yy < H && xx >= 0 && xx < W)
      v = xb[(size_t)(cq * 32 + p) * HW + yy * 64 + xx];
    xs[p][rr][c] = v;
  }
  __syncthreads();

  float acc[5];
#pragma unroll
  for (int s = 0; s < 5; ++s) {
    int oc = ocg + 4 * s;
    acc[s] = (cq == 0 && oc < OFFC) ? ob[oc] : 0.f;
  }

  for (int p = 0; p < 32; ++p) {
    __half2 xv[9];
#pragma unroll
    for (int rr = 0; rr < 3; ++rr)
#pragma unroll
      for (int dxx = 0; dxx < 3; ++dxx) xv[rr * 3 + dxx] = u2h(xs[p][rr][j + dxx]);
#pragma unroll
    for (int s = 0; s < 5; ++s) {
      int oc = ocg + 4 * s;
      if (oc < OFFC) {
        const unsigned* wp = owp + ((size_t)oc * 128 + cq * 32 + p) * 9;   // uniform -> s_load
        __half2 h = __floats2half2_rn(0.f, 0.f);
#pragma unroll
        for (int k = 0; k < 9; ++k) h = __hfma2(xv[k], u2h(wp[k]), h);
        float2 f = __half22float2(h);
        acc[s] += f.x + f.y;
      }
    }
  }
#pragma unroll
  for (int s = 0; s < 5; ++s) {
    int oc = ocg + 4 * s;
    if (oc < OFFC)
      off4[(((size_t)(cq * B + b) * OFFC + oc) << 12) + (i << 6) + j] = acc[s];
  }
}

// ---------------- fused deformable conv (fp16 MFMA, dbuf patch + dbuf tile, 1 barrier/chunk) ----
// Steady state chunk c: issue loads(c+1) | gather(c)->s_su[c&1] | MFMA(c-1)<-s_su[(c-1)&1]
//                       | write patch(c+1) | barrier.  MFMA + HBM latency hide under gather.
__launch_bounds__(512)
__global__ void deform_mfma_k(const unsigned* __restrict__ xp, const float* __restrict__ off4,
                              const __half* __restrict__ wf,
                              const float* __restrict__ bias,
                              float* __restrict__ y, float* __restrict__ stats) {
  int jh = blockIdx.x & 1;
  int i  = (blockIdx.x >> 1) & 63;
  int b  = blockIdx.x >> 7;
  int t = threadIdx.x;
  int lane = t & 63, wv = t >> 6;        // 8 waves
  int cidx = lane & 15, r = lane >> 4;   // MFMA lane decomposition
  int jl = t & 31, cg = t >> 5;          // gather mapping: pixel jl, channel-pair cg (0..15)

  __shared__ __align__(16) unsigned s_md[K2][32][4];   // half2 bilinear weights (pre-broadcast)
  __shared__ __align__(8)  unsigned s_mf[K2][32][2];   // pb+flags, fallback
  __shared__ unsigned s_pt[2][16 * PSTR];              // patch dbuf: 16 pairs x (6x44 +pad)
  __shared__ __align__(16) unsigned s_su[2][32][148];  // sampled tile dbuf (fp16 pairs)
  __shared__ float rs_[8], rq_[8];
  // LDS total: 4608+2304+34304+37888+64 = 79168 B -> 2 blocks/CU

  const unsigned* xb = xp + (size_t)b * 128 * HW;
  int br = i - 2, bc = (jh << 5) - 5;     // patch origin: rows br..br+5, cols bc..bc+43

  // patch load/store offsets; tail (e=8, jl>=8) clamp-duplicates slot 263 (benign same-value dup)
  int gof[9], wof[9];
#pragma unroll
  for (int e = 0; e < 9; ++e) {
    int pos = min(jl + (e << 5), 263);
    int row = pos / 44, col = pos - row * 44;
    int rr = min(max(br + row, 0), H - 1);
    int c2 = min(max(bc + col, 0), W - 1);
    gof[e] = rr * 64 + c2;
    wof[e] = row * 44 + col;
  }

  // prologue: issue patch-0 loads (metadata compute below hides their latency)
  unsigned l[9];
  {
    const unsigned* bp = xb + (size_t)cg * HW;
#pragma unroll
    for (int e = 0; e < 9; ++e) l[e] = bp[gof[e]];
  }

  // Phase A: metadata (9 taps x 32 px)
  for (int idx = t; idx < K2 * 32; idx += 512) {
    int k = idx >> 5, jj = idx & 31;
    int j = (jh << 5) + jj;
    float dy = 0.f, dx = 0.f;
#pragma unroll
    for (int cq = 0; cq < 4; ++cq) {
      const float* p = off4 + (((size_t)(cq * B + b) * OFFC) << 12) + (i << 6) + j;
      dy += p[(2 * k) << 12];
      dx += p[(2 * k + 1) << 12];
    }
    float py = (float)(i + (k / 3) - 1) + dy;
    float px = (float)(j + (k % 3) - 1) + dx;
    float y0f = floorf(py), x0f = floorf(px);
    float wy1 = py - y0f, wx1 = px - x0f;
    float wy0 = 1.f - wy1, wx0 = 1.f - wx1;
    int y0 = (int)y0f, x0 = (int)x0f;
    if (y0 < 0 || y0 >= H)         wy0 = 0.f;
    if (y0 + 1 < 0 || y0 + 1 >= H) wy1 = 0.f;
    if (x0 < 0 || x0 >= W)         wx0 = 0.f;
    if (x0 + 1 < 0 || x0 + 1 >= W) wx1 = 0.f;
    int y0c = min(max(y0, 0), H - 1), y1c = min(max(y0 + 1, 0), H - 1);
    int x0c = min(max(x0, 0), W - 1), x1c = min(max(x0 + 1, 0), W - 1);
    int dys = y1c - y0c, dxs = x1c - x0c;
    uint4 wq;
    wq.x = h2u(__float2half2_rn(wy0 * wx0));
    wq.y = h2u(__float2half2_rn(wy0 * wx1));
    wq.z = h2u(__float2half2_rn(wy1 * wx0));
    wq.w = h2u(__float2half2_rn(wy1 * wx1));
    *reinterpret_cast<uint4*>(&s_md[k][jj][0]) = wq;
    bool ip = (y0c >= br) && (y1c <= br + 5) && (x0c >= bc) && (x1c <= bc + 43);
    unsigned pb = (unsigned)((y0c - br) * 44 + (x0c - bc));
    s_mf[k][jj][0] = (ip ? (pb & 0xfff) : 0u) | ((unsigned)dxs << 12) | ((unsigned)dys << 13) |
                     (ip ? 0u : 0x4000u);
    s_mf[k][jj][1] = (unsigned)(y0c * 64 + x0c) | ((unsigned)dxs << 12) | ((unsigned)dys << 13);
  }

  // write patch 0
#pragma unroll
  for (int e = 0; e < 9; ++e) s_pt[0][cg * PSTR + wof[e]] = l[e];
  __syncthreads();

  // hoist pb/fallback words (chunk-invariant) to registers
  unsigned pbf[9], fbk[9];
#pragma unroll
  for (int k = 0; k < K2; ++k) {
    uint2 mm = *reinterpret_cast<const uint2*>(&s_mf[k][jl][0]);
    pbf[k] = mm.x; fbk[k] = mm.y;
  }

  f32x4 acc[2][2];
#pragma unroll
  for (int m = 0; m < 2; ++m) {
    acc[m][0] = {0.f, 0.f, 0.f, 0.f};
    acc[m][1] = {0.f, 0.f, 0.f, 0.f};
  }
  int ob_ = wv * 32;
  const __half* w0p = wf + (size_t)(ob_ + cidx) * 2304;
  const __half* w1p = w0p + 16 * 2304;

  for (int cb = 0; cb < 8; ++cb) {
    int cur = cb & 1;
    if (cb < 7) {                                   // issue next patch loads early
      const unsigned* bp = xb + (size_t)((cb + 1) * 16 + cg) * HW;
#pragma unroll
      for (int e = 0; e < 9; ++e) l[e] = bp[gof[e]];
    }
    // gather+interp chunk cb from patch[cur] -> s_su[cur]
    {
      const unsigned* pt = &s_pt[cur][cg * PSTR];
#pragma unroll
      for (int k = 0; k < K2; ++k) {
        uint4 m = *reinterpret_cast<const uint4*>(&s_md[k][jl][0]);
        unsigned z = pbf[k];
        int pb = z & 0xfff;
        int dxx = (z >> 12) & 1, dyy = ((z >> 13) & 1) ? 44 : 0;
        __half2 q00 = u2h(pt[pb]),        q01 = u2h(pt[pb + dxx]);
        __half2 q10 = u2h(pt[pb + dyy]),  q11 = u2h(pt[pb + dyy + dxx]);
        __half2 v = __hmul2(u2h(m.x), q00);
        v = __hfma2(u2h(m.y), q01, v);
        v = __hfma2(u2h(m.z), q10, v);
        v = __hfma2(u2h(m.w), q11, v);
        if (z & 0x4000u) {                          // rare: clamped corners escape patch
          unsigned f = fbk[k];
          int i00 = f & 0xfff;
          int fdx = (f >> 12) & 1, fdy = ((f >> 13) & 1) ? 64 : 0;
          const unsigned* xc = xb + (size_t)(cb * 16 + cg) * HW;
          v = __hmul2(u2h(m.x), u2h(xc[i00]));
          v = __hfma2(u2h(m.y), u2h(xc[i00 + fdx]), v);
          v = __hfma2(u2h(m.z), u2h(xc[i00 + fdy]), v);
          v = __hfma2(u2h(m.w), u2h(xc[i00 + fdy + fdx]), v);
        }
        s_su[cur][jl][k * 16 + cg] = h2u(v);
      }
    }
    // MFMA chunk cb-1 from s_su[cur^1] -- overlaps the gather above (no barrier between)
    if (cb > 0) {
      int kb0 = (cb - 1) * 288 + r * 8;
#pragma unroll 3
      for (int kk = 0; kk < 9; ++kk) {
        f16x8 a0 = *(const f16x8*)&s_su[cur ^ 1][cidx][kk * 16 + r * 4];
        f16x8 a1 = *(const f16x8*)&s_su[cur ^ 1][16 + cidx][kk * 16 + r * 4];
        f16x8 b0 = *(const f16x8*)&w0p[kb0 + kk * 32];
        f16x8 b1 = *(const f16x8*)&w1p[kb0 + kk * 32];
        acc[0][0] = __builtin_amdgcn_mfma_f32_16x16x32_f16(a0, b0, acc[0][0], 0, 0, 0);
        acc[1][0] = __builtin_amdgcn_mfma_f32_16x16x32_f16(a1, b0, acc[1][0], 0, 0, 0);
        acc[0][1] = __builtin_amdgcn_mfma_f32_16x16x32_f16(a0, b1, acc[0][1], 0, 0, 0);
        acc[1][1] = __builtin_amdgcn_mfma_f32_16x16x32_f16(a1, b1, acc[1][1], 0, 0, 0);
      }
    }
    // write next patch (write-late: vmcnt drains here, hidden under gather+MFMA above)
    if (cb < 7) {
#pragma unroll
      for (int e = 0; e < 9; ++e) s_pt[cur ^ 1][cg * PSTR + wof[e]] = l[e];
    }
    __syncthreads();
  }
  // epilogue MFMA: chunk 7 from s_su[1]
  {
    int kb0 = 7 * 288 + r * 8;
#pragma unroll 3
    for (int kk = 0; kk < 9; ++kk) {
      f16x8 a0 = *(const f16x8*)&s_su[1][cidx][kk * 16 + r * 4];
      f16x8 a1 = *(const f16x8*)&s_su[1][16 + cidx][kk * 16 + r * 4];
      f16x8 b0 = *(const f16x8*)&w0p[kb0 + kk * 32];
      f16x8 b1 = *(const f16x8*)&w1p[kb0 + kk * 32];
      acc[0][0] = __builtin_amdgcn_mfma_f32_16x16x32_f16(a0, b0, acc[0][0], 0, 0, 0);
      acc[1][0] = __builtin_amdgcn_mfma_f32_16x16x32_f16(a1, b0, acc[1][0], 0, 0, 0);
      acc[0][1] = __builtin_amdgcn_mfma_f32_16x16x32_f16(a0, b1, acc[0][1], 0, 0, 0);
      acc[1][1] = __builtin_amdgcn_mfma_f32_16x16x32_f16(a1, b1, acc[1][1], 0, 0, 0);
    }
  }

  // epilogue: bias, store, GN partial stats
  float bv0 = bias[ob_ + cidx], bv1 = bias[ob_ + 16 + cidx];
  float psum = 0.f, psq = 0.f;
#pragma unroll
  for (int m = 0; m < 2; ++m) {
#pragma unroll
    for (int n = 0; n < 2; ++n) {
      int o = ob_ + n * 16 + cidx;
      float bv = n ? bv1 : bv0;
      float4 vv;
      vv.x = acc[m][n][0] + bv; vv.y = acc[m][n][1] + bv;
      vv.z = acc[m][n][2] + bv; vv.w = acc[m][n][3] + bv;
      *reinterpret_cast<float4*>(y + (((size_t)(b * C + o)) << 12) + (i << 6) + (jh << 5) + m * 16 + r * 4) = vv;
      psum += vv.x + vv.y + vv.z + vv.w;
      psq  += vv.x * vv.x + vv.y * vv.y + vv.z * vv.z + vv.w * vv.w;
    }
  }
#pragma unroll
  for (int d = 32; d > 0; d >>= 1) {
    psum += __shfl_down(psum, d);
    psq  += __shfl_down(psq, d);
  }
  if (lane == 0) { rs_[wv] = psum; rq_[wv] = psq; }
  __syncthreads();
  if (t == 0) {
    float a = 0.f, s2 = 0.f;
    for (int u = 0; u < 8; ++u) { a += rs_[u]; s2 += rq_[u]; }
    atomicAdd(&stats[b * 2],     a);
    atomicAdd(&stats[b * 2 + 1], s2);
  }
}

// ---------------- GN + relu -> fp16-pair output (layer1 -> layer2 input) ----------------
__global__ void gn_pair_k(const float* __restrict__ yv, const float* __restrict__ stats,
                          const float* __restrict__ g, const float* __restrict__ be,
                          unsigned* __restrict__ outp) {
  const float inv = 1.f / (float)(C * HW);
  int idx = blockIdx.x * 256 + threadIdx.x;      // B*128*1024
  int px4 = idx & 1023, c2 = (idx >> 10) & 127, b = idx >> 17;
  float mean = stats[b * 2] * inv;
  float var  = stats[b * 2 + 1] * inv - mean * mean;
  float rs   = rsqrtf(var + 1e-5f);
  float a0 = g[2 * c2] * rs,     bb0 = be[2 * c2] - mean * a0;
  float a1 = g[2 * c2 + 1] * rs, bb1 = be[2 * c2 + 1] - mean * a1;
  const float4 v0 = *reinterpret_cast<const float4*>(yv + (((size_t)(b * 256 + 2 * c2)) << 12) + px4 * 4);
  const float4 v1 = *reinterpret_cast<const float4*>(yv + (((size_t)(b * 256 + 2 * c2 + 1)) << 12) + px4 * 4);
  uint4 o;
  o.x = packh2(fmaxf(0.f, v0.x * a0 + bb0), fmaxf(0.f, v1.x * a1 + bb1));
  o.y = packh2(fmaxf(0.f, v0.y * a0 + bb0), fmaxf(0.f, v1.y * a1 + bb1));
  o.z = packh2(fmaxf(0.f, v0.z * a0 + bb0), fmaxf(0.f, v1.z * a1 + bb1));
  o.w = packh2(fmaxf(0.f, v0.w * a0 + bb0), fmaxf(0.f, v1.w * a1 + bb1));
  *reinterpret_cast<uint4*>(outp + (((size_t)(b * 128 + c2)) << 12) + px4 * 4) = o;
}

// ---------------- fused: h2 = relu(gn2(yv)); z = h2 + x (in-place ok); stats(z) ----------------
__global__ void gn2res_k(const float* __restrict__ yv, const float* __restrict__ stats,
                         const float* __restrict__ g, const float* __restrict__ be,
                         const float* __restrict__ x, float* __restrict__ z,
                         float* __restrict__ stats3) {
  const float inv = 1.f / (float)(C * HW);
  int b = blockIdx.x >> 8;
  int seg = blockIdx.x & 255;
  size_t base = ((size_t)b << 20) + ((size_t)seg << 12);
  int t = threadIdx.x;
  float mean = stats[b * 2] * inv;
  float var  = stats[b * 2 + 1] * inv - mean * mean;
  float rsv  = rsqrtf(var + 1e-5f);
  int c = seg;                                    // seg 0..255 == channel
  float a = g[c] * rsv, bb = be[c] - mean * a;
  float psum = 0.f, psq = 0.f;
#pragma unroll
  for (int u = 0; u < 4; ++u) {
    size_t e = base + (size_t)(u * 256 + t) * 4;
    float4 v = *reinterpret_cast<const float4*>(yv + e);
    float4 xr = *reinterpret_cast<const float4*>(x + e);
    float4 rr;
    rr.x = fmaxf(0.f, v.x * a + bb) + xr.x;
    rr.y = fmaxf(0.f, v.y * a + bb) + xr.y;
    rr.z = fmaxf(0.f, v.z * a + bb) + xr.z;
    rr.w = fmaxf(0.f, v.w * a + bb) + xr.w;
    *reinterpret_cast<float4*>(z + e) = rr;
    psum += rr.x + rr.y + rr.z + rr.w;
    psq  += rr.x * rr.x + rr.y * rr.y + rr.z * rr.z + rr.w * rr.w;
  }
#pragma unroll
  for (int d = 32; d > 0; d >>= 1) {
    psum += __shfl_down(psum, d);
    psq  += __shfl_down(psq, d);
  }
  __shared__ float rs_[4], rq_[4];
  int wid = t >> 6, lane = t & 63;
  if (lane == 0) { rs_[wid] = psum; rq_[wid] = psq; }
  __syncthreads();
  if (t == 0) {
    float aa = 0.f, s2 = 0.f;
    for (int u = 0; u < 4; ++u) { aa += rs_[u]; s2 += rq_[u]; }
    atomicAdd(&stats3[b * 2],     aa);
    atomicAdd(&stats3[b * 2 + 1], s2);
  }
}

// ---------------- final group-norm (fp32 out) ----------------
__global__ void gn_k(const float* __restrict__ yv, const float* __restrict__ stats,
                     const float* __restrict__ g, const float* __restrict__ be,
                     float* __restrict__ outp) {
  const float inv = 1.f / (float)(C * HW);
  int stride = gridDim.x * blockDim.x;
  int total4 = B * C * HW / 4;
  for (int idx = blockIdx.x * blockDim.x + threadIdx.x; idx < total4; idx += stride) {
    int e = idx << 2;
    int b = e >> 20;
    int c = (e >> 12) & 255;
    float mean = stats[b * 2] * inv;
    float var  = stats[b * 2 + 1] * inv - mean * mean;
    float rs   = rsqrtf(var + 1e-5f);
    float a  = g[c] * rs;
    float b2 = be[c] - mean * a;
    float4 v = *reinterpret_cast<const float4*>(yv + e);
    float4 rr;
    rr.x = v.x * a + b2; rr.y = v.y * a + b2; rr.z = v.z * a + b2; rr.w = v.w * a + b2;
    *reinterpret_cast<float4*>(outp + e) = rr;
  }
}

extern "C" void kernel_launch(void* const* d_in, const int* in_sizes, int n_in,
                              void* d_out, int out_size, void* d_ws, size_t ws_size,
                              hipStream_t stream) {
  const float* x   = (const float*)d_in[0];
  const float* ow1 = (const float*)d_in[1];
  const float* ob1 = (const float*)d_in[2];
  const float* dw1 = (const float*)d_in[3];
  const float* db1 = (const float*)d_in[4];
  const float* g1  = (const float*)d_in[5];
  const float* b1  = (const float*)d_in[6];
  const float* ow2 = (const float*)d_in[7];
  const float* ob2 = (const float*)d_in[8];
  const float* dw2 = (const float*)d_in[9];
  const float* db2 = (const float*)d_in[10];
  const float* g2  = (const float*)d_in[11];
  const float* b2  = (const float*)d_in[12];
  const float* g3  = (const float*)d_in[13];
  const float* b3  = (const float*)d_in[14];

  float* ws   = (float*)d_ws;
  float* off4 = ws;                                   // 1179648 f
  float* yb   = ws + 1179648;                         // 4194304 f
  float* st   = ws + 1179648 + 4194304;               // 32 f
  unsigned* xh = (unsigned*)(ws + 5373984);           // 2097152 u32
  unsigned* hh = (unsigned*)(ws + 7471136);           // 2097152 u32
  __half* wf1 = (__half*)(ws + 9568288);              // 589824 fp16 = 294912 f
  __half* wf2 = (__half*)(ws + 9863200);
  unsigned* owp1 = (unsigned*)(ws + 10158112);        // 20736 u32
  unsigned* owp2 = (unsigned*)(ws + 10178848);
  float* outp = (float*)d_out;

  hipMemsetAsync(st, 0, 32 * sizeof(float), stream);
  cvt_wf16_reord_k<<<2304, 256, 0, stream>>>(dw1, wf1);
  cvt_wf16_reord_k<<<2304, 256, 0, stream>>>(dw2, wf2);
  cvt_owpair_k<<<81, 256, 0, stream>>>(ow1, owp1);
  cvt_owpair_k<<<81, 256, 0, stream>>>(ow2, owp2);
  cvt_xpair_k<<<2048, 256, 0, stream>>>(x, xh);

  // layer 1
  offset_conv_k<<<1024, 256, 0, stream>>>(xh, owp1, ob1, off4);
  deform_mfma_k<<<512, 512, 0, stream>>>(xh, off4, wf1, db1, yb, st + 0);
  gn_pair_k<<<2048, 256, 0, stream>>>(yb, st + 0, g1, b1, hh);
  // layer 2
  offset_conv_k<<<1024, 256, 0, stream>>>(hh, owp2, ob2, off4);
  deform_mfma_k<<<512, 512, 0, stream>>>(hh, off4, wf2, db2, yb, st + 8);
  // fused gn2 + relu + residual (in-place on yb) + final stats
  gn2res_k<<<1024, 256, 0, stream>>>(yb, st + 8, g2, b2, x, yb, st + 16);
  gn_k<<<2048, 256, 0, stream>>>(yb, st + 16, g3, b3, outp);
}